// Round 3
// baseline (102.963 us; speedup 1.0000x reference)
//
#include <hip/hip_runtime.h>
#include <hip/hip_bf16.h>

#define NF 16
#define NH 32
#define LOG2E  1.44269504088896340736f

typedef short bf16x8 __attribute__((ext_vector_type(8)));
typedef float f32x16 __attribute__((ext_vector_type(16)));

#if __has_builtin(__builtin_amdgcn_exp2f)
#define EXP2(x) __builtin_amdgcn_exp2f(x)
#else
#define EXP2(x) exp2f(x)
#endif

__device__ __forceinline__ short f2bf(float f) {
    __hip_bfloat16 b = __float2bfloat16(f);  // RNE
    return *reinterpret_cast<short*>(&b);
}

__device__ __forceinline__ bf16x8 cvt8(float4 a, float4 b) {
    bf16x8 r;
    r[0] = f2bf(a.x); r[1] = f2bf(a.y); r[2] = f2bf(a.z); r[3] = f2bf(a.w);
    r[4] = f2bf(b.x); r[5] = f2bf(b.y); r[6] = f2bf(b.z); r[7] = f2bf(b.w);
    return r;
}

// sigmoid with pre-scaled arg: input already multiplied by log2(e)
__device__ __forceinline__ float sig2(float v) {
    return __builtin_amdgcn_rcpf(1.0f + EXP2(-v));
}
// tanh with pre-scaled arg: input already multiplied by 2*log2(e)
__device__ __forceinline__ float tanh2(float v) {
    return 1.0f - 2.0f * __builtin_amdgcn_rcpf(1.0f + EXP2(v));
}

// ---------------------------------------------------------------------------
// Prep: pack W' = [Wx; Wh; bias; 0-pad] (64x32 per gate, scaled by log2e per
// gate; gate 2 by 2*log2e) into MFMA A-operand fragments (bf16).
// Fragment layout (v_mfma_f32_32x32x16_bf16 A): lane l holds row (l&31)=j,
// k=(l>>5)*8+e. kstep ks covers k = ks*16..ks*16+15 where
//   k 0..15 = Wx rows, 16..47 = Wh rows, 48 = bias (pairs with input 1.0).
// Wpack index: (((g*4)+ks)*64 + l)*8 + e   -> 4*4*64*8 shorts = 16384 B.
// wcs: scaled peephole weights [3][32] floats at byte 16384.
// ---------------------------------------------------------------------------
__global__ void prep_kernel(const float* __restrict__ Wx, const float* __restrict__ Wh,
                            const float* __restrict__ bx, const float* __restrict__ bh,
                            const float* __restrict__ bg, const float* __restrict__ wc,
                            short* __restrict__ Wpack, float* __restrict__ wcs)
{
    int t = blockIdx.x * blockDim.x + threadIdx.x;
    if (t < 4 * 4 * 64) {
        int g  = t >> 8;
        int ks = (t >> 6) & 3;
        int l  = t & 63;
        int col  = l & 31;           // j
        int half = l >> 5;
        float scale = (g == 2) ? 2.0f * LOG2E : LOG2E;
        #pragma unroll
        for (int e = 0; e < 8; ++e) {
            int gk = ks * 16 + half * 8 + e;
            float w;
            if (gk < NF)            w = Wx[(g * NF + gk) * NH + col];
            else if (gk < NF + NH)  w = Wh[(g * NH + (gk - NF)) * NH + col];
            else if (gk == 48)      w = bx[g * NH + col] + bh[g * NH + col] + bg[g * NH + col];
            else                    w = 0.0f;
            Wpack[t * 8 + e] = f2bf(w * scale);
        }
    }
    if (t < 3 * NH) {
        wcs[t] = wc[t] * LOG2E;
    }
}

// ---------------------------------------------------------------------------
// Main: one wave = 32 nodes. Swapped-operand MFMA: D = W'^T-frag (A) x
// inputs (B) so D[row=j][col=node]. Lane l owns node nb+(l&31); its 16 regs
// hold j = (r&3) + 8*(r>>2) + 4*(l>>5). K=64: x(16) + h(32) + bias(1) + pad.
// ---------------------------------------------------------------------------
__global__ __launch_bounds__(256) void lstm_mfma_kernel(
    const float* __restrict__ x,
    const float* __restrict__ hin,
    const float* __restrict__ cin,
    const float* __restrict__ Wlin,  // [32]
    const float* __restrict__ blin,  // [1]
    const short* __restrict__ Wpack,
    const float* __restrict__ wcs,
    float* __restrict__ out,
    float* __restrict__ h0o,
    float* __restrict__ co,
    int N)
{
    const int lane = threadIdx.x & 63;
    const int wave = threadIdx.x >> 6;
    const long nb = ((long)blockIdx.x * 4 + wave) * 32;
    if (nb >= N) return;

    const int col  = lane & 31;   // node within tile
    const int half = lane >> 5;
    const size_t node = (size_t)(nb + col);

    // ---- input fragments (B operand): lane holds col=node, k=(l>>5)*8+e ----
    bf16x8 a0, a1, a2;
    {
        const float* px  = x   + node * NF + half * 8;
        const float* ph  = hin + node * NH + half * 8;
        const float* ph2 = ph + 16;
        a0 = cvt8(*(const float4*)px,  *(const float4*)(px + 4));   // k 0..15  = x
        a1 = cvt8(*(const float4*)ph,  *(const float4*)(ph + 4));   // k 16..31 = h[0..15]
        a2 = cvt8(*(const float4*)ph2, *(const float4*)(ph2 + 4));  // k 32..47 = h[16..31]
    }
    // virtual input: 1.0 at k=48 (bias), 0 elsewhere
    bf16x8 a3;
    #pragma unroll
    for (int e = 0; e < 8; ++e) a3[e] = 0;
    if (half == 0) a3[0] = (short)0x3F80;  // bf16 1.0

    // ---- prefetch c (HBM) before the MFMA block ----
    float4 cv4[4];
    #pragma unroll
    for (int jg = 0; jg < 4; ++jg)
        cv4[jg] = *(const float4*)(cin + node * NH + jg * 8 + 4 * half);

    // ---- weight fragments (A operand; L1/L2-resident) ----
    bf16x8 wf[4][4];
    #pragma unroll
    for (int g = 0; g < 4; ++g)
        #pragma unroll
        for (int ks = 0; ks < 4; ++ks)
            wf[g][ks] = *(const bf16x8*)(Wpack + (((g * 4) + ks) * 64 + lane) * 8);

    // ---- 16 MFMAs: 4 gates x K=64 (bias folded into ks=3) ----
    f32x16 acc[4];
    #pragma unroll
    for (int g = 0; g < 4; ++g) {
        #pragma unroll
        for (int r = 0; r < 16; ++r) acc[g][r] = 0.0f;
        acc[g] = __builtin_amdgcn_mfma_f32_32x32x16_bf16(wf[g][0], a0, acc[g], 0, 0, 0);
        acc[g] = __builtin_amdgcn_mfma_f32_32x32x16_bf16(wf[g][1], a1, acc[g], 0, 0, 0);
        acc[g] = __builtin_amdgcn_mfma_f32_32x32x16_bf16(wf[g][2], a2, acc[g], 0, 0, 0);
        acc[g] = __builtin_amdgcn_mfma_f32_32x32x16_bf16(wf[g][3], a3, acc[g], 0, 0, 0);
    }

    // ---- epilogue: lane owns node; regs walk j in groups of 4 consecutive ----
    float outacc = 0.0f;
    const float c2l = 2.0f * LOG2E;
    #pragma unroll
    for (int jg = 0; jg < 4; ++jg) {
        const int jbase = jg * 8 + 4 * half;
        const float4 w0 = *(const float4*)(wcs + 0 * NH + jbase);
        const float4 w1 = *(const float4*)(wcs + 1 * NH + jbase);
        const float4 w2 = *(const float4*)(wcs + 2 * NH + jbase);
        const float4 wl = *(const float4*)(Wlin + jbase);
        float h4[4], c4[4];
        #pragma unroll
        for (int q = 0; q < 4; ++q) {
            const int r = jg * 4 + q;  // j = jbase + q
            const float ci = ((const float*)&cv4[jg])[q];
            const float ig = sig2(fmaf(((const float*)&w0)[q], ci, acc[0][r]));
            const float fg = sig2(fmaf(((const float*)&w1)[q], ci, acc[1][r]));
            const float tg = tanh2(acc[2][r]);
            const float cn = fg * ci + ig * tg;
            const float og = sig2(fmaf(((const float*)&w2)[q], cn, acc[3][r]));
            const float hh = og * tanh2(cn * c2l);
            c4[q] = cn;
            h4[q] = hh;
            outacc = fmaf(fmaxf(hh, 0.0f), ((const float*)&wl)[q], outacc);
        }
        *(float4*)(h0o + node * NH + jbase) = make_float4(h4[0], h4[1], h4[2], h4[3]);
        *(float4*)(co  + node * NH + jbase) = make_float4(c4[0], c4[1], c4[2], c4[3]);
    }

    // ---- out[node] = sum over all 32 j: combine the two halves ----
    outacc += __shfl_xor(outacc, 32, 64);
    if (half == 0) out[node] = outacc + blin[0];
}

extern "C" void kernel_launch(void* const* d_in, const int* in_sizes, int n_in,
                              void* d_out, int out_size, void* d_ws, size_t ws_size,
                              hipStream_t stream) {
    const float* x    = (const float*)d_in[0];
    // d_in[1] = edge_index (unused, K=1 ChebConv), d_in[2] = edge_weight (unused)
    const float* h    = (const float*)d_in[3];
    const float* c    = (const float*)d_in[4];
    const float* Wx   = (const float*)d_in[5];
    const float* bx   = (const float*)d_in[6];
    const float* Wh   = (const float*)d_in[7];
    const float* bh   = (const float*)d_in[8];
    const float* wc   = (const float*)d_in[9];
    const float* bg   = (const float*)d_in[10];
    const float* Wlin = (const float*)d_in[11];
    const float* blin = (const float*)d_in[12];

    const int N = in_sizes[0] / NF;  // 500000

    float* out = (float*)d_out;             // [N,1]
    float* h0o = out + N;                   // [N,32]
    float* co  = h0o + (size_t)N * NH;      // [N,32]

    short* Wpack = (short*)d_ws;                                   // 16384 B
    float* wcs   = (float*)((char*)d_ws + 4 * 4 * 64 * 8 * sizeof(short));

    prep_kernel<<<4, 256, 0, stream>>>(Wx, Wh, bx, bh, bg, wc, Wpack, wcs);

    const int nodes_per_block = 4 * NH;  // 4 waves x 32 nodes
    const int grid = (N + nodes_per_block - 1) / nodes_per_block;
    lstm_mfma_kernel<<<grid, 256, 0, stream>>>(
        x, h, c, Wlin, blin, Wpack, wcs, out, h0o, co, N);
}

// Round 4
// 73.957 us; speedup vs baseline: 1.3922x; 1.3922x over previous
//
#include <hip/hip_runtime.h>
#include <hip/hip_bf16.h>

#define NF 16
#define NH 32
#define LOG2E  1.44269504088896340736f
#define LROW   68   // LDS row stride (floats): 32 h + 32 c + 4 pad (16B-aligned, 2-way-free banks)

typedef short bf16x8 __attribute__((ext_vector_type(8)));
typedef float f32x16 __attribute__((ext_vector_type(16)));

#if __has_builtin(__builtin_amdgcn_exp2f)
#define EXP2(x) __builtin_amdgcn_exp2f(x)
#else
#define EXP2(x) exp2f(x)
#endif

__device__ __forceinline__ short f2bf(float f) {
    __hip_bfloat16 b = __float2bfloat16(f);  // RNE
    return *reinterpret_cast<short*>(&b);
}

__device__ __forceinline__ bf16x8 cvt8(float4 a, float4 b) {
    bf16x8 r;
    r[0] = f2bf(a.x); r[1] = f2bf(a.y); r[2] = f2bf(a.z); r[3] = f2bf(a.w);
    r[4] = f2bf(b.x); r[5] = f2bf(b.y); r[6] = f2bf(b.z); r[7] = f2bf(b.w);
    return r;
}

// sigmoid with pre-scaled arg: input already multiplied by log2(e)
__device__ __forceinline__ float sig2(float v) {
    return __builtin_amdgcn_rcpf(1.0f + EXP2(-v));
}
// tanh with pre-scaled arg: input already multiplied by 2*log2(e)
__device__ __forceinline__ float tanh2(float v) {
    return 1.0f - 2.0f * __builtin_amdgcn_rcpf(1.0f + EXP2(v));
}

// ---------------------------------------------------------------------------
// Prep: pack W' = [Wx; Wh; bias; 0-pad] (64x32 per gate, scaled by log2e per
// gate; gate 2 by 2*log2e) into MFMA A-operand fragments (bf16).
// A layout (v_mfma_f32_32x32x16_bf16): lane l holds row (l&31)=j,
// k=(l>>5)*8+e. kstep ks covers k = ks*16..ks*16+15 where
//   k 0..15 = Wx rows, 16..47 = Wh rows, 48 = bias (pairs with input 1.0).
// Wpack index: (((g*4)+ks)*64 + l)*8 + e   -> 4*4*64*8 shorts = 16384 B.
// wcs: scaled peephole weights [3][32] floats at byte 16384.
// ---------------------------------------------------------------------------
__global__ void prep_kernel(const float* __restrict__ Wx, const float* __restrict__ Wh,
                            const float* __restrict__ bx, const float* __restrict__ bh,
                            const float* __restrict__ bg, const float* __restrict__ wc,
                            short* __restrict__ Wpack, float* __restrict__ wcs)
{
    int t = blockIdx.x * blockDim.x + threadIdx.x;
    if (t < 4 * 4 * 64) {
        int g  = t >> 8;
        int ks = (t >> 6) & 3;
        int l  = t & 63;
        int col  = l & 31;           // j
        int half = l >> 5;
        float scale = (g == 2) ? 2.0f * LOG2E : LOG2E;
        #pragma unroll
        for (int e = 0; e < 8; ++e) {
            int gk = ks * 16 + half * 8 + e;
            float w;
            if (gk < NF)            w = Wx[(g * NF + gk) * NH + col];
            else if (gk < NF + NH)  w = Wh[(g * NH + (gk - NF)) * NH + col];
            else if (gk == 48)      w = bx[g * NH + col] + bh[g * NH + col] + bg[g * NH + col];
            else                    w = 0.0f;
            Wpack[t * 8 + e] = f2bf(w * scale);
        }
    }
    if (t < 3 * NH) {
        wcs[t] = wc[t] * LOG2E;
    }
}

// ---------------------------------------------------------------------------
// Main: one wave = 32 nodes. Swapped-operand MFMA: D = W'-frag (A) x
// inputs (B) so D[row=j][col=node]. Lane l owns node nb+(l&31); its 16 regs
// hold j = (r&3) + 8*(r>>2) + 4*(l>>5). K=64: x(16) + h(32) + bias(1) + pad.
// h0/c outputs go through a per-wave LDS transpose so global stores are
// fully-coalesced dwordx4 rows (round-3 direct float4 stores caused 32%
// HBM write amplification from 16B-at-128B-stride scatter).
// ---------------------------------------------------------------------------
__global__ __launch_bounds__(256) void lstm_mfma_kernel(
    const float* __restrict__ x,
    const float* __restrict__ hin,
    const float* __restrict__ cin,
    const float* __restrict__ Wlin,  // [32]
    const float* __restrict__ blin,  // [1]
    const short* __restrict__ Wpack,
    const float* __restrict__ wcs,
    float* __restrict__ out,
    float* __restrict__ h0o,
    float* __restrict__ co,
    int N)
{
    __shared__ float sbuf[4][NH * LROW];  // per-wave 8704 B, 34816 B total

    const int lane = threadIdx.x & 63;
    const int wave = threadIdx.x >> 6;
    const long nb = ((long)blockIdx.x * 4 + wave) * 32;
    if (nb >= N) return;   // N % 32 == 0, so whole waves only; no barrier below

    float* ws = sbuf[wave];

    const int col  = lane & 31;   // node within tile
    const int half = lane >> 5;
    const size_t node = (size_t)(nb + col);

    // ---- input fragments (B operand): lane holds col=node, k=(l>>5)*8+e ----
    bf16x8 a0, a1, a2;
    {
        const float* px  = x   + node * NF + half * 8;
        const float* ph  = hin + node * NH + half * 8;
        const float* ph2 = ph + 16;
        a0 = cvt8(*(const float4*)px,  *(const float4*)(px + 4));   // k 0..15  = x
        a1 = cvt8(*(const float4*)ph,  *(const float4*)(ph + 4));   // k 16..31 = h[0..15]
        a2 = cvt8(*(const float4*)ph2, *(const float4*)(ph2 + 4));  // k 32..47 = h[16..31]
    }
    // virtual input: 1.0 at k=48 (bias), 0 elsewhere
    bf16x8 a3;
    #pragma unroll
    for (int e = 0; e < 8; ++e) a3[e] = 0;
    if (half == 0) a3[0] = (short)0x3F80;  // bf16 1.0

    // ---- prefetch c (HBM) before the MFMA block ----
    float4 cv4[4];
    #pragma unroll
    for (int jg = 0; jg < 4; ++jg)
        cv4[jg] = *(const float4*)(cin + node * NH + jg * 8 + 4 * half);

    // ---- weight fragments (A operand; L1/L2-resident) ----
    bf16x8 wf[4][4];
    #pragma unroll
    for (int g = 0; g < 4; ++g)
        #pragma unroll
        for (int ks = 0; ks < 4; ++ks)
            wf[g][ks] = *(const bf16x8*)(Wpack + (((g * 4) + ks) * 64 + lane) * 8);

    // ---- 16 MFMAs: 4 gates x K=64 (bias folded into ks=3) ----
    f32x16 acc[4];
    #pragma unroll
    for (int g = 0; g < 4; ++g) {
        #pragma unroll
        for (int r = 0; r < 16; ++r) acc[g][r] = 0.0f;
        acc[g] = __builtin_amdgcn_mfma_f32_32x32x16_bf16(wf[g][0], a0, acc[g], 0, 0, 0);
        acc[g] = __builtin_amdgcn_mfma_f32_32x32x16_bf16(wf[g][1], a1, acc[g], 0, 0, 0);
        acc[g] = __builtin_amdgcn_mfma_f32_32x32x16_bf16(wf[g][2], a2, acc[g], 0, 0, 0);
        acc[g] = __builtin_amdgcn_mfma_f32_32x32x16_bf16(wf[g][3], a3, acc[g], 0, 0, 0);
    }

    // ---- epilogue: gates -> h/c into per-wave LDS tile ----
    float outacc = 0.0f;
    const float c2l = 2.0f * LOG2E;
    #pragma unroll
    for (int jg = 0; jg < 4; ++jg) {
        const int jbase = jg * 8 + 4 * half;
        const float4 w0 = *(const float4*)(wcs + 0 * NH + jbase);
        const float4 w1 = *(const float4*)(wcs + 1 * NH + jbase);
        const float4 w2 = *(const float4*)(wcs + 2 * NH + jbase);
        const float4 wl = *(const float4*)(Wlin + jbase);
        float h4[4], c4[4];
        #pragma unroll
        for (int q = 0; q < 4; ++q) {
            const int r = jg * 4 + q;  // j = jbase + q
            const float ci = ((const float*)&cv4[jg])[q];
            const float ig = sig2(fmaf(((const float*)&w0)[q], ci, acc[0][r]));
            const float fg = sig2(fmaf(((const float*)&w1)[q], ci, acc[1][r]));
            const float tg = tanh2(acc[2][r]);
            const float cn = fg * ci + ig * tg;
            const float og = sig2(fmaf(((const float*)&w2)[q], cn, acc[3][r]));
            const float hh = og * tanh2(cn * c2l);
            c4[q] = cn;
            h4[q] = hh;
            outacc = fmaf(fmaxf(hh, 0.0f), ((const float*)&wl)[q], outacc);
        }
        *(float4*)&ws[col * LROW + jbase]      = make_float4(h4[0], h4[1], h4[2], h4[3]);
        *(float4*)&ws[col * LROW + NH + jbase] = make_float4(c4[0], c4[1], c4[2], c4[3]);
    }

    // ---- coalesced write-back: 4+4 x 1KB dwordx4 rows per wave ----
    // (compiler inserts the lgkmcnt wait; buffer is private to this wave)
    float* hrow = h0o + (size_t)nb * NH;
    float* crow = co  + (size_t)nb * NH;
    #pragma unroll
    for (int rep = 0; rep < 4; ++rep) {
        const int t  = lane + rep * 64;   // float4 index 0..255 within 32x32 tile
        const int nd = t >> 3;
        const int j4 = (t & 7) * 4;
        float4 vh = *(const float4*)&ws[nd * LROW + j4];
        float4 vc = *(const float4*)&ws[nd * LROW + NH + j4];
        *(float4*)(hrow + t * 4) = vh;
        *(float4*)(crow + t * 4) = vc;
    }

    // ---- out[node] = sum over all 32 j: combine the two halves ----
    outacc += __shfl_xor(outacc, 32, 64);
    if (half == 0) out[node] = outacc + blin[0];
}

extern "C" void kernel_launch(void* const* d_in, const int* in_sizes, int n_in,
                              void* d_out, int out_size, void* d_ws, size_t ws_size,
                              hipStream_t stream) {
    const float* x    = (const float*)d_in[0];
    // d_in[1] = edge_index (unused, K=1 ChebConv), d_in[2] = edge_weight (unused)
    const float* h    = (const float*)d_in[3];
    const float* c    = (const float*)d_in[4];
    const float* Wx   = (const float*)d_in[5];
    const float* bx   = (const float*)d_in[6];
    const float* Wh   = (const float*)d_in[7];
    const float* bh   = (const float*)d_in[8];
    const float* wc   = (const float*)d_in[9];
    const float* bg   = (const float*)d_in[10];
    const float* Wlin = (const float*)d_in[11];
    const float* blin = (const float*)d_in[12];

    const int N = in_sizes[0] / NF;  // 500000

    float* out = (float*)d_out;             // [N,1]
    float* h0o = out + N;                   // [N,32]
    float* co  = h0o + (size_t)N * NH;      // [N,32]

    short* Wpack = (short*)d_ws;                                   // 16384 B
    float* wcs   = (float*)((char*)d_ws + 4 * 4 * 64 * 8 * sizeof(short));

    prep_kernel<<<4, 256, 0, stream>>>(Wx, Wh, bx, bh, bg, wc, Wpack, wcs);

    const int nodes_per_block = 4 * NH;  // 4 waves x 32 nodes
    const int grid = (N + nodes_per_block - 1) / nodes_per_block;
    lstm_mfma_kernel<<<grid, 256, 0, stream>>>(
        x, h, c, Wlin, blin, Wpack, wcs, out, h0o, co, N);
}

// Round 5
// 65.878 us; speedup vs baseline: 1.5629x; 1.1226x over previous
//
#include <hip/hip_runtime.h>
#include <hip/hip_bf16.h>

#define NF 16
#define NH 32
#define LOG2E  1.44269504088896340736f
#define TILE_NODES 32

// per-wave LDS staging buffer layout (float words)
#define T_WORDS 2560   // x 512 + h 1024 + c 1024 words = 10 KB
#define XW 0
#define HW 512
#define CW 1536
// output-transpose overlay (reuses consumed input space, stride 36 floats)
#define HOUT 0         // words 0..1151
#define COUT 1152      // words 1152..2303

typedef short bf16x8 __attribute__((ext_vector_type(8)));
typedef float f32x16 __attribute__((ext_vector_type(16)));

#if __has_builtin(__builtin_amdgcn_exp2f)
#define EXP2(x) __builtin_amdgcn_exp2f(x)
#else
#define EXP2(x) exp2f(x)
#endif

__device__ __forceinline__ short f2bf(float f) {
    __hip_bfloat16 b = __float2bfloat16(f);  // RNE
    return *reinterpret_cast<short*>(&b);
}

__device__ __forceinline__ bf16x8 cvt8(float4 a, float4 b) {
    bf16x8 r;
    r[0] = f2bf(a.x); r[1] = f2bf(a.y); r[2] = f2bf(a.z); r[3] = f2bf(a.w);
    r[4] = f2bf(b.x); r[5] = f2bf(b.y); r[6] = f2bf(b.z); r[7] = f2bf(b.w);
    return r;
}

__device__ __forceinline__ float sig2(float v) {   // arg pre-scaled by log2e
    return __builtin_amdgcn_rcpf(1.0f + EXP2(-v));
}
__device__ __forceinline__ float tanh2(float v) {  // arg pre-scaled by 2*log2e
    return 1.0f - 2.0f * __builtin_amdgcn_rcpf(1.0f + EXP2(v));
}

// async global->LDS, 16B per lane, LDS dest = uniform base + lane*16
__device__ __forceinline__ void gload_lds16(const float* g, float* l) {
    __builtin_amdgcn_global_load_lds(
        (const __attribute__((address_space(1))) void*)g,
        (__attribute__((address_space(3))) void*)l, 16, 0, 0);
}

struct Frags { bf16x8 w[4][4]; bf16x8 a3; };

// ---------------------------------------------------------------------------
// Prep: pack W' = [Wx; Wh; bias; pad] (64x32 per gate, pre-scaled by log2e,
// gate 2 by 2*log2e) into MFMA A-operand fragments. wcs = scaled peephole.
// ---------------------------------------------------------------------------
__global__ void prep_kernel(const float* __restrict__ Wx, const float* __restrict__ Wh,
                            const float* __restrict__ bx, const float* __restrict__ bh,
                            const float* __restrict__ bg, const float* __restrict__ wc,
                            short* __restrict__ Wpack, float* __restrict__ wcs)
{
    int t = blockIdx.x * blockDim.x + threadIdx.x;
    if (t < 4 * 4 * 64) {
        int g  = t >> 8;
        int ks = (t >> 6) & 3;
        int l  = t & 63;
        int col  = l & 31;
        int half = l >> 5;
        float scale = (g == 2) ? 2.0f * LOG2E : LOG2E;
        #pragma unroll
        for (int e = 0; e < 8; ++e) {
            int gk = ks * 16 + half * 8 + e;
            float w;
            if (gk < NF)            w = Wx[(g * NF + gk) * NH + col];
            else if (gk < NF + NH)  w = Wh[(g * NH + (gk - NF)) * NH + col];
            else if (gk == 48)      w = bx[g * NH + col] + bh[g * NH + col] + bg[g * NH + col];
            else                    w = 0.0f;
            Wpack[t * 8 + e] = f2bf(w * scale);
        }
    }
    if (t < 3 * NH) wcs[t] = wc[t] * LOG2E;
}

// ---------------------------------------------------------------------------
// Prefetch one 32-node tile (x,h,c) into a wave-private LDS buffer via 10
// global_load_lds. Source per-lane f4 index is XOR-pre-swizzled within each
// row so the (linear) LDS image reads conflict-free at 128B row stride.
// ---------------------------------------------------------------------------
__device__ __forceinline__ void prefetch_tile(const float* __restrict__ x,
                                              const float* __restrict__ hin,
                                              const float* __restrict__ cin,
                                              long nb, float* ws, int lane)
{
    asm volatile("" ::: "memory");   // pin issue order around the DMA group
    const float* xb = x   + nb * NF;
    const float* hb = hin + nb * NH;
    const float* cb = cin + nb * NH;
    #pragma unroll
    for (int i = 0; i < 2; ++i) {          // x: 2KB, rows of 4 f4
        int u = i * 64 + lane;
        int src = (u & ~3) | ((u & 3) ^ ((u >> 2) & 3));
        gload_lds16(xb + src * 4, ws + XW + i * 256);
    }
    #pragma unroll
    for (int i = 0; i < 4; ++i) {          // h: 4KB, rows of 8 f4
        int u = i * 64 + lane;
        int src = (u & ~7) | ((u & 7) ^ ((u >> 3) & 7));
        gload_lds16(hb + src * 4, ws + HW + i * 256);
    }
    #pragma unroll
    for (int i = 0; i < 4; ++i) {          // c: 4KB, rows of 8 f4
        int u = i * 64 + lane;
        int src = (u & ~7) | ((u & 7) ^ ((u >> 3) & 7));
        gload_lds16(cb + src * 4, ws + CW + i * 256);
    }
    asm volatile("" ::: "memory");
}

// ---------------------------------------------------------------------------
// Compute one 32-node tile from a staged LDS buffer. Swapped-operand MFMA:
// D[row=j][col=node]; lane owns node nb+(lane&31).
// ---------------------------------------------------------------------------
__device__ __forceinline__ void do_tile(float* ws, long nb, const Frags& F,
                                        const float* __restrict__ wcs,
                                        const float* __restrict__ Wlin, float bl,
                                        float* __restrict__ out,
                                        float* __restrict__ h0o,
                                        float* __restrict__ co, int lane)
{
    const int col  = lane & 31;
    const int half = lane >> 5;
    const int c3 = col & 3, c7 = col & 7;

    // wait for THIS buffer's 10 fills (oldest); leave the newest 10 (other
    // buffer's fills, issued just before this call) in flight.
    asm volatile("s_waitcnt vmcnt(10)" ::: "memory");

    // ---- fragment reads from LDS (swizzle matches prefetch source) ----
    float4 x0 = *(const float4*)&ws[XW + (col * 4 + ((2 * half)     ^ c3)) * 4];
    float4 x1 = *(const float4*)&ws[XW + (col * 4 + ((2 * half + 1) ^ c3)) * 4];
    float4 h0 = *(const float4*)&ws[HW + (col * 8 + ((2 * half)     ^ c7)) * 4];
    float4 h1 = *(const float4*)&ws[HW + (col * 8 + ((2 * half + 1) ^ c7)) * 4];
    float4 h2 = *(const float4*)&ws[HW + (col * 8 + ((4 + 2 * half) ^ c7)) * 4];
    float4 h3 = *(const float4*)&ws[HW + (col * 8 + ((5 + 2 * half) ^ c7)) * 4];
    bf16x8 a0 = cvt8(x0, x1), a1 = cvt8(h0, h1), a2 = cvt8(h2, h3);

    float4 cv4[4];
    #pragma unroll
    for (int jg = 0; jg < 4; ++jg)
        cv4[jg] = *(const float4*)&ws[CW + (col * 8 + ((2 * jg + half) ^ c7)) * 4];

    // ---- 16 MFMAs: 4 gates x K=64 (bias folded) ----
    f32x16 acc[4];
    #pragma unroll
    for (int g = 0; g < 4; ++g) {
        #pragma unroll
        for (int r = 0; r < 16; ++r) acc[g][r] = 0.0f;
        acc[g] = __builtin_amdgcn_mfma_f32_32x32x16_bf16(F.w[g][0], a0,   acc[g], 0, 0, 0);
        acc[g] = __builtin_amdgcn_mfma_f32_32x32x16_bf16(F.w[g][1], a1,   acc[g], 0, 0, 0);
        acc[g] = __builtin_amdgcn_mfma_f32_32x32x16_bf16(F.w[g][2], a2,   acc[g], 0, 0, 0);
        acc[g] = __builtin_amdgcn_mfma_f32_32x32x16_bf16(F.w[g][3], F.a3, acc[g], 0, 0, 0);
    }

    // ---- epilogue: gates -> h/c into LDS overlay (inputs already consumed) ----
    float outacc = 0.0f;
    const float c2l = 2.0f * LOG2E;
    #pragma unroll
    for (int jg = 0; jg < 4; ++jg) {
        const int jbase = jg * 8 + 4 * half;
        const float4 w0 = *(const float4*)(wcs + 0 * NH + jbase);
        const float4 w1 = *(const float4*)(wcs + 1 * NH + jbase);
        const float4 w2 = *(const float4*)(wcs + 2 * NH + jbase);
        const float4 wl = *(const float4*)(Wlin + jbase);
        float h4[4], c4[4];
        #pragma unroll
        for (int q = 0; q < 4; ++q) {
            const int r = jg * 4 + q;
            const float ci = ((const float*)&cv4[jg])[q];
            const float ig = sig2(fmaf(((const float*)&w0)[q], ci, acc[0][r]));
            const float fg = sig2(fmaf(((const float*)&w1)[q], ci, acc[1][r]));
            const float tg = tanh2(acc[2][r]);
            const float cn = fg * ci + ig * tg;
            const float og = sig2(fmaf(((const float*)&w2)[q], cn, acc[3][r]));
            const float hh = og * tanh2(cn * c2l);
            c4[q] = cn;
            h4[q] = hh;
            outacc = fmaf(fmaxf(hh, 0.0f), ((const float*)&wl)[q], outacc);
        }
        *(float4*)&ws[HOUT + col * 36 + jbase] = make_float4(h4[0], h4[1], h4[2], h4[3]);
        *(float4*)&ws[COUT + col * 36 + jbase] = make_float4(c4[0], c4[1], c4[2], c4[3]);
    }

    // ---- coalesced write-back: 4+4 x 1KB dwordx4 rows per wave ----
    float* hrow = h0o + nb * NH;
    float* crow = co  + nb * NH;
    #pragma unroll
    for (int rep = 0; rep < 4; ++rep) {
        const int tt = lane + rep * 64;
        const int nd = tt >> 3, j4 = (tt & 7) * 4;
        float4 vh = *(const float4*)&ws[HOUT + nd * 36 + j4];
        float4 vc = *(const float4*)&ws[COUT + nd * 36 + j4];
        *(float4*)(hrow + tt * 4) = vh;
        *(float4*)(crow + tt * 4) = vc;
    }

    outacc += __shfl_xor(outacc, 32, 64);
    if (half == 0) out[nb + col] = outacc + bl;
}

// ---------------------------------------------------------------------------
// Persistent grid-stride pipeline: 512 blocks x 4 waves; each wave loops over
// tiles with stride = total waves, double-buffering LDS fills (A/B are
// distinct shared objects so the compiler can prove no aliasing).
// ---------------------------------------------------------------------------
__global__ __launch_bounds__(256, 2) void lstm_pipe_kernel(
    const float* __restrict__ x, const float* __restrict__ hin,
    const float* __restrict__ cin,
    const float* __restrict__ Wlin, const float* __restrict__ blin,
    const short* __restrict__ Wpack, const float* __restrict__ wcs,
    float* __restrict__ out, float* __restrict__ h0o, float* __restrict__ co,
    int ntiles, int wstride)
{
    __shared__ float bufA[4][T_WORDS];   // 40 KB
    __shared__ float bufB[4][T_WORDS];   // 40 KB

    const int lane = threadIdx.x & 63;
    const int wave = threadIdx.x >> 6;
    float* wsA = bufA[wave];
    float* wsB = bufB[wave];

    // one-time per wave: weight fragments (64 VGPR, budget 256 at 2 waves/EU)
    Frags F;
    #pragma unroll
    for (int g = 0; g < 4; ++g)
        #pragma unroll
        for (int ks = 0; ks < 4; ++ks)
            F.w[g][ks] = *(const bf16x8*)(Wpack + (((g * 4) + ks) * 64 + lane) * 8);
    #pragma unroll
    for (int e = 0; e < 8; ++e) F.a3[e] = 0;
    if ((lane >> 5) == 0) F.a3[0] = (short)0x3F80;  // bf16 1.0 at k=48
    const float bl = blin[0];

    int t = blockIdx.x * 4 + wave;
    if (t >= ntiles) return;
    prefetch_tile(x, hin, cin, (long)t * TILE_NODES, wsA, lane);

    for (;;) {
        int t1 = t + wstride;
        if (t1 < ntiles) prefetch_tile(x, hin, cin, (long)t1 * TILE_NODES, wsB, lane);
        do_tile(wsA, (long)t * TILE_NODES, F, wcs, Wlin, bl, out, h0o, co, lane);
        if (t1 >= ntiles) break;

        int t2 = t1 + wstride;
        if (t2 < ntiles) prefetch_tile(x, hin, cin, (long)t2 * TILE_NODES, wsA, lane);
        do_tile(wsB, (long)t1 * TILE_NODES, F, wcs, Wlin, bl, out, h0o, co, lane);
        if (t2 >= ntiles) break;
        t = t2;
    }
}

extern "C" void kernel_launch(void* const* d_in, const int* in_sizes, int n_in,
                              void* d_out, int out_size, void* d_ws, size_t ws_size,
                              hipStream_t stream) {
    const float* x    = (const float*)d_in[0];
    // d_in[1] = edge_index (unused, K=1 ChebConv), d_in[2] = edge_weight (unused)
    const float* h    = (const float*)d_in[3];
    const float* c    = (const float*)d_in[4];
    const float* Wx   = (const float*)d_in[5];
    const float* bx   = (const float*)d_in[6];
    const float* Wh   = (const float*)d_in[7];
    const float* bh   = (const float*)d_in[8];
    const float* wc   = (const float*)d_in[9];
    const float* bg   = (const float*)d_in[10];
    const float* Wlin = (const float*)d_in[11];
    const float* blin = (const float*)d_in[12];

    const int N = in_sizes[0] / NF;          // 500000
    const int ntiles = N / TILE_NODES;       // 15625 (N % 32 == 0)

    float* out = (float*)d_out;              // [N,1]
    float* h0o = out + N;                    // [N,32]
    float* co  = h0o + (size_t)N * NH;       // [N,32]

    short* Wpack = (short*)d_ws;                                   // 16384 B
    float* wcs   = (float*)((char*)d_ws + 4 * 4 * 64 * 8 * sizeof(short));

    prep_kernel<<<4, 256, 0, stream>>>(Wx, Wh, bx, bh, bg, wc, Wpack, wcs);

    const int grid = 512;                    // 2 blocks/CU (LDS-exact)
    const int wstride = grid * 4;            // total waves
    lstm_pipe_kernel<<<grid, 256, 0, stream>>>(
        x, h, c, Wlin, blin, Wpack, wcs, out, h0o, co, ntiles, wstride);
}

// Round 7
// 58.177 us; speedup vs baseline: 1.7698x; 1.1324x over previous
//
#include <hip/hip_runtime.h>
#include <hip/hip_bf16.h>

#define NF 16
#define NH 32
#define LOG2E  1.44269504088896340736f
#define TILE_NODES 32

// per-wave LDS staging buffer layout (float words)
#define T_WORDS 2560   // x 512 + h 1024 + c 1024 words = 10 KB
#define XW 0
#define HW 512
#define CW 1536
// output-transpose overlay (reuses consumed input space, stride 36 floats)
#define HOUT 0         // words 0..1151
#define COUT 1152      // words 1152..2303

typedef short bf16x8 __attribute__((ext_vector_type(8)));
typedef float f32x16 __attribute__((ext_vector_type(16)));
typedef float f32x4  __attribute__((ext_vector_type(4)));   // clang-native for nontemporal builtin

#if __has_builtin(__builtin_amdgcn_exp2f)
#define EXP2(x) __builtin_amdgcn_exp2f(x)
#else
#define EXP2(x) exp2f(x)
#endif

__device__ __forceinline__ short f2bf(float f) {
    __hip_bfloat16 b = __float2bfloat16(f);  // RNE
    return *reinterpret_cast<short*>(&b);
}

__device__ __forceinline__ bf16x8 cvt8(float4 a, float4 b) {
    bf16x8 r;
    r[0] = f2bf(a.x); r[1] = f2bf(a.y); r[2] = f2bf(a.z); r[3] = f2bf(a.w);
    r[4] = f2bf(b.x); r[5] = f2bf(b.y); r[6] = f2bf(b.z); r[7] = f2bf(b.w);
    return r;
}

__device__ __forceinline__ float sig2(float v) {   // arg pre-scaled by log2e
    return __builtin_amdgcn_rcpf(1.0f + EXP2(-v));
}
__device__ __forceinline__ float tanh2(float v) {  // arg pre-scaled by 2*log2e
    return 1.0f - 2.0f * __builtin_amdgcn_rcpf(1.0f + EXP2(v));
}

// async global->LDS, 16B per lane, LDS dest = uniform base + lane*16
__device__ __forceinline__ void gload_lds16(const float* g, float* l) {
    __builtin_amdgcn_global_load_lds(
        (const __attribute__((address_space(1))) void*)g,
        (__attribute__((address_space(3))) void*)l, 16, 0, 0);
}

// non-temporal 16B store: outputs are never re-read -> don't pollute L2/L3.
// (must use clang ext_vector type; HIP float4 class is rejected by the builtin)
__device__ __forceinline__ void nt_store4(float* p, float4 v) {
    f32x4 w = { v.x, v.y, v.z, v.w };
    __builtin_nontemporal_store(w, (f32x4*)p);
}

struct Frags { bf16x8 w[4][4]; bf16x8 a3; };

// ---------------------------------------------------------------------------
// Prep: pack W' = [Wx; Wh; bias; pad] (64x32 per gate, pre-scaled by log2e,
// gate 2 by 2*log2e) into MFMA A-operand fragments. wcs = scaled peephole.
// ---------------------------------------------------------------------------
__global__ void prep_kernel(const float* __restrict__ Wx, const float* __restrict__ Wh,
                            const float* __restrict__ bx, const float* __restrict__ bh,
                            const float* __restrict__ bg, const float* __restrict__ wc,
                            short* __restrict__ Wpack, float* __restrict__ wcs)
{
    int t = blockIdx.x * blockDim.x + threadIdx.x;
    if (t < 4 * 4 * 64) {
        int g  = t >> 8;
        int ks = (t >> 6) & 3;
        int l  = t & 63;
        int col  = l & 31;
        int half = l >> 5;
        float scale = (g == 2) ? 2.0f * LOG2E : LOG2E;
        #pragma unroll
        for (int e = 0; e < 8; ++e) {
            int gk = ks * 16 + half * 8 + e;
            float w;
            if (gk < NF)            w = Wx[(g * NF + gk) * NH + col];
            else if (gk < NF + NH)  w = Wh[(g * NH + (gk - NF)) * NH + col];
            else if (gk == 48)      w = bx[g * NH + col] + bh[g * NH + col] + bg[g * NH + col];
            else                    w = 0.0f;
            Wpack[t * 8 + e] = f2bf(w * scale);
        }
    }
    if (t < 3 * NH) wcs[t] = wc[t] * LOG2E;
}

// ---------------------------------------------------------------------------
// Prefetch one 32-node tile (x,h,c) into a wave-private LDS buffer via 10
// global_load_lds. Per-lane source offsets are precomputed (XOR-pre-swizzled
// within each row so the linear LDS image reads conflict-free at 128B rows).
// ---------------------------------------------------------------------------
__device__ __forceinline__ void prefetch_tile(const float* __restrict__ x,
                                              const float* __restrict__ hin,
                                              const float* __restrict__ cin,
                                              long nb, float* ws,
                                              const int* xoff, const int* hoff)
{
    asm volatile("" ::: "memory");   // pin issue order around the DMA group
    const float* xb = x   + nb * NF;
    const float* hb = hin + nb * NH;
    const float* cb = cin + nb * NH;
    #pragma unroll
    for (int i = 0; i < 2; ++i) gload_lds16(xb + xoff[i], ws + XW + i * 256);
    #pragma unroll
    for (int i = 0; i < 4; ++i) gload_lds16(hb + hoff[i], ws + HW + i * 256);
    #pragma unroll
    for (int i = 0; i < 4; ++i) gload_lds16(cb + hoff[i], ws + CW + i * 256);
    asm volatile("" ::: "memory");
}

// ---------------------------------------------------------------------------
// Consume one staged 32-node tile. Swapped-operand MFMA: D[row=j][col=node];
// lane owns node nb+(lane&31). Outputs transposed through the (consumed)
// input LDS region, stored non-temporally as coalesced 1KB rows.
// ---------------------------------------------------------------------------
__device__ __forceinline__ void do_tile(float* ws, long nb, const Frags& F,
                                        const float* __restrict__ wcs,
                                        const float* __restrict__ Wlin, float bl,
                                        float* __restrict__ out,
                                        float* __restrict__ h0o,
                                        float* __restrict__ co, int lane)
{
    const int col  = lane & 31;
    const int half = lane >> 5;
    const int c3 = col & 3, c7 = col & 7;

    // ---- fragment reads from LDS (swizzle matches prefetch source) ----
    float4 x0 = *(const float4*)&ws[XW + (col * 4 + ((2 * half)     ^ c3)) * 4];
    float4 x1 = *(const float4*)&ws[XW + (col * 4 + ((2 * half + 1) ^ c3)) * 4];
    float4 h0 = *(const float4*)&ws[HW + (col * 8 + ((2 * half)     ^ c7)) * 4];
    float4 h1 = *(const float4*)&ws[HW + (col * 8 + ((2 * half + 1) ^ c7)) * 4];
    float4 h2 = *(const float4*)&ws[HW + (col * 8 + ((4 + 2 * half) ^ c7)) * 4];
    float4 h3 = *(const float4*)&ws[HW + (col * 8 + ((5 + 2 * half) ^ c7)) * 4];
    bf16x8 a0 = cvt8(x0, x1), a1 = cvt8(h0, h1), a2 = cvt8(h2, h3);

    float4 cv4[4];
    #pragma unroll
    for (int jg = 0; jg < 4; ++jg)
        cv4[jg] = *(const float4*)&ws[CW + (col * 8 + ((2 * jg + half) ^ c7)) * 4];

    // ---- 16 MFMAs: 4 gates x K=64 (bias folded) ----
    f32x16 acc[4];
    #pragma unroll
    for (int g = 0; g < 4; ++g) {
        #pragma unroll
        for (int r = 0; r < 16; ++r) acc[g][r] = 0.0f;
        acc[g] = __builtin_amdgcn_mfma_f32_32x32x16_bf16(F.w[g][0], a0,   acc[g], 0, 0, 0);
        acc[g] = __builtin_amdgcn_mfma_f32_32x32x16_bf16(F.w[g][1], a1,   acc[g], 0, 0, 0);
        acc[g] = __builtin_amdgcn_mfma_f32_32x32x16_bf16(F.w[g][2], a2,   acc[g], 0, 0, 0);
        acc[g] = __builtin_amdgcn_mfma_f32_32x32x16_bf16(F.w[g][3], F.a3, acc[g], 0, 0, 0);
    }

    // ---- epilogue: gates -> h/c into LDS overlay (inputs already consumed) ----
    float outacc = 0.0f;
    const float c2l = 2.0f * LOG2E;
    #pragma unroll
    for (int jg = 0; jg < 4; ++jg) {
        const int jbase = jg * 8 + 4 * half;
        const float4 w0 = *(const float4*)(wcs + 0 * NH + jbase);
        const float4 w1 = *(const float4*)(wcs + 1 * NH + jbase);
        const float4 w2 = *(const float4*)(wcs + 2 * NH + jbase);
        const float4 wl = *(const float4*)(Wlin + jbase);
        float h4[4], c4[4];
        #pragma unroll
        for (int q = 0; q < 4; ++q) {
            const int r = jg * 4 + q;
            const float ci = ((const float*)&cv4[jg])[q];
            const float ig = sig2(fmaf(((const float*)&w0)[q], ci, acc[0][r]));
            const float fg = sig2(fmaf(((const float*)&w1)[q], ci, acc[1][r]));
            const float tg = tanh2(acc[2][r]);
            const float cn = fg * ci + ig * tg;
            const float og = sig2(fmaf(((const float*)&w2)[q], cn, acc[3][r]));
            const float hh = og * tanh2(cn * c2l);
            c4[q] = cn;
            h4[q] = hh;
            outacc = fmaf(fmaxf(hh, 0.0f), ((const float*)&wl)[q], outacc);
        }
        *(float4*)&ws[HOUT + col * 36 + jbase] = make_float4(h4[0], h4[1], h4[2], h4[3]);
        *(float4*)&ws[COUT + col * 36 + jbase] = make_float4(c4[0], c4[1], c4[2], c4[3]);
    }

    // ---- coalesced non-temporal write-back: 4+4 x 1KB dwordx4 rows ----
    float* hrow = h0o + nb * NH;
    float* crow = co  + nb * NH;
    #pragma unroll
    for (int rep = 0; rep < 4; ++rep) {
        const int tt = lane + rep * 64;
        const int nd = tt >> 3, j4 = (tt & 7) * 4;
        float4 vh = *(const float4*)&ws[HOUT + nd * 36 + j4];
        float4 vc = *(const float4*)&ws[COUT + nd * 36 + j4];
        nt_store4(hrow + tt * 4, vh);
        nt_store4(crow + tt * 4, vc);
    }

    outacc += __shfl_xor(outacc, 32, 64);
    if (half == 0) __builtin_nontemporal_store(outacc + bl, &out[nb + col]);
}

// ---------------------------------------------------------------------------
// Persistent grid-stride pipeline, FIFO-exact vmcnt accounting:
//   prologue: prefetch L(t)->A, L(t+S)->B                    [20 out]
//   iter 1:   vmcnt(10) drains exactly L(t)                  (peeled count)
//   iter k:   vmcnt(19) drains exactly the tile's 10 loads;
//             previous stores get a 2-tile retirement leash.
//   each iter: consume cur -> 9 NT stores -> prefetch t+2S into cur -> swap.
//   tail prefetches are clamped (duplicate last tile) to keep counts uniform.
// ---------------------------------------------------------------------------
__global__ __launch_bounds__(256, 2) void lstm_pipe_kernel(
    const float* __restrict__ x, const float* __restrict__ hin,
    const float* __restrict__ cin,
    const float* __restrict__ Wlin, const float* __restrict__ blin,
    const short* __restrict__ Wpack, const float* __restrict__ wcs,
    float* __restrict__ out, float* __restrict__ h0o, float* __restrict__ co,
    int ntiles, int wstride)
{
    __shared__ float bufA[4][T_WORDS];   // 40 KB
    __shared__ float bufB[4][T_WORDS];   // 40 KB

    const int lane = threadIdx.x & 63;
    const int wave = threadIdx.x >> 6;
    float* cur = bufA[wave];
    float* oth = bufB[wave];

    // one-time per wave: weight fragments (64 VGPR)
    Frags F;
    #pragma unroll
    for (int g = 0; g < 4; ++g)
        #pragma unroll
        for (int ks = 0; ks < 4; ++ks)
            F.w[g][ks] = *(const bf16x8*)(Wpack + (((g * 4) + ks) * 64 + lane) * 8);
    #pragma unroll
    for (int e = 0; e < 8; ++e) F.a3[e] = 0;
    if ((lane >> 5) == 0) F.a3[0] = (short)0x3F80;  // bf16 1.0 at k=48
    const float bl = blin[0];

    // one-time per wave: swizzled DMA source offsets (lane-constant)
    int xoff[2], hoff[4];
    #pragma unroll
    for (int i = 0; i < 2; ++i) {
        int u = i * 64 + lane;
        xoff[i] = ((u & ~3) | ((u & 3) ^ ((u >> 2) & 3))) * 4;
    }
    #pragma unroll
    for (int i = 0; i < 4; ++i) {
        int u = i * 64 + lane;
        hoff[i] = ((u & ~7) | ((u & 7) ^ ((u >> 3) & 7))) * 4;
    }

    const int S = wstride;
    const int last = ntiles - 1;
    int t = blockIdx.x * 4 + wave;       // 2048 waves <= ntiles, so t < ntiles

    prefetch_tile(x, hin, cin, (long)t * TILE_NODES, cur, xoff, hoff);
    {
        int t1 = t + S; if (t1 > last) t1 = last;   // clamped (dup harmless)
        prefetch_tile(x, hin, cin, (long)t1 * TILE_NODES, oth, xoff, hoff);
    }

    bool first = true;
    for (;;) {
        if (first) { asm volatile("s_waitcnt vmcnt(10)" ::: "memory"); first = false; }
        else       { asm volatile("s_waitcnt vmcnt(19)" ::: "memory"); }

        do_tile(cur, (long)t * TILE_NODES, F, wcs, Wlin, bl, out, h0o, co, lane);

        int tn = t + 2 * S; if (tn > last) tn = last;  // clamped dup keeps counts uniform
        prefetch_tile(x, hin, cin, (long)tn * TILE_NODES, cur, xoff, hoff);

        t += S;
        if (t >= ntiles) break;
        float* tmp = cur; cur = oth; oth = tmp;
    }
}

extern "C" void kernel_launch(void* const* d_in, const int* in_sizes, int n_in,
                              void* d_out, int out_size, void* d_ws, size_t ws_size,
                              hipStream_t stream) {
    const float* x    = (const float*)d_in[0];
    // d_in[1] = edge_index (unused, K=1 ChebConv), d_in[2] = edge_weight (unused)
    const float* h    = (const float*)d_in[3];
    const float* c    = (const float*)d_in[4];
    const float* Wx   = (const float*)d_in[5];
    const float* bx   = (const float*)d_in[6];
    const float* Wh   = (const float*)d_in[7];
    const float* bh   = (const float*)d_in[8];
    const float* wc   = (const float*)d_in[9];
    const float* bg   = (const float*)d_in[10];
    const float* Wlin = (const float*)d_in[11];
    const float* blin = (const float*)d_in[12];

    const int N = in_sizes[0] / NF;          // 500000
    const int ntiles = N / TILE_NODES;       // 15625 (N % 32 == 0)

    float* out = (float*)d_out;              // [N,1]
    float* h0o = out + N;                    // [N,32]
    float* co  = h0o + (size_t)N * NH;       // [N,32]

    short* Wpack = (short*)d_ws;                                   // 16384 B
    float* wcs   = (float*)((char*)d_ws + 4 * 4 * 64 * 8 * sizeof(short));

    prep_kernel<<<4, 256, 0, stream>>>(Wx, Wh, bx, bh, bg, wc, Wpack, wcs);

    const int grid = 512;                    // 2 blocks/CU (LDS-exact)
    const int wstride = grid * 4;            // total waves = 2048
    lstm_pipe_kernel<<<grid, 256, 0, stream>>>(
        x, h, c, Wlin, blin, Wpack, wcs, out, h0o, co, ntiles, wstride);
}